// Round 8
// baseline (100.277 us; speedup 1.0000x reference)
//
#include <hip/hip_runtime.h>
#include <stdint.h>

typedef unsigned short u16;
typedef unsigned short u16x8 __attribute__((ext_vector_type(8)));
typedef short s16x8 __attribute__((ext_vector_type(8)));
typedef float f32x4 __attribute__((ext_vector_type(4)));

__device__ __forceinline__ float b2f(u16 u){ return __uint_as_float(((unsigned)u)<<16); }
__device__ __forceinline__ u16 f2b(float f){
  unsigned u = __float_as_uint(f);
  u += 0x7FFF + ((u>>16)&1);            // round-to-nearest-even
  return (u16)(u>>16);
}
__device__ __forceinline__ float sigm(float x){ return 1.0f/(1.0f+__expf(-x)); }
__device__ __forceinline__ float tanhf_(float x){ return 2.0f/(1.0f+__expf(-2.0f*x)) - 1.0f; }

__device__ __forceinline__ f32x4 mf(s16x8 a, s16x8 b, f32x4 c){
  return __builtin_amdgcn_mfma_f32_16x16x32_bf16(a, b, c, 0, 0, 0);
}

// ---------------------------------------------------------------------------
// prep: pack weights into exact bf16 B-fragment order.
//   frag layout: lane holds B[k = ks*32 + (lane>>4)*8 + j][n = nt*16 + (lane&15)], j=0..7
//   pack8[] regions (u16x8 index): att_W1 [0,1024), W_ih^T [1024,3072),
//                                  W_hh^T [3072,5120), mlp_W1 [5120,5632)
// ---------------------------------------------------------------------------
__global__ void prep_kernel(const float* __restrict__ att_W1, const float* __restrict__ W_ih,
                            const float* __restrict__ W_hh, const float* __restrict__ mlp_W1,
                            u16* __restrict__ pack){
  int t = blockIdx.x*blockDim.x + threadIdx.x;
  if (t >= 5632) return;
  int lane = t & 63;
  int kb = (lane>>4)<<3;
  int nl = lane & 15;
  u16x8 o;
  if (t < 1024){
    int f = t>>6; int nt=f>>2, ks=f&3;
    int n = (nt<<4)+nl;
    #pragma unroll
    for (int j=0;j<8;j++){ int k = ks*32+kb+j; o[j] = f2b(att_W1[k*64+n]); }
  } else if (t < 3072){
    int f=(t-1024)>>6; int nt=f>>1, ks=f&1;
    int n=(nt<<4)+nl;
    #pragma unroll
    for (int j=0;j<8;j++){ int k=ks*32+kb+j; o[j]=f2b(W_ih[n*64+k]); }   // B = W_ih^T
  } else if (t < 5120){
    int f=(t-3072)>>6; int nt=f>>1, ks=f&1;
    int n=(nt<<4)+nl;
    #pragma unroll
    for (int j=0;j<8;j++){ int k=ks*32+kb+j; o[j]=f2b(W_hh[n*64+k]); }   // B = W_hh^T
  } else {
    int f=(t-5120)>>6; int nt=f>>1, ks=f&1;
    int n=(nt<<4)+nl;
    #pragma unroll
    for (int j=0;j<8;j++){ int k=ks*32+kb+j; o[j]=f2b(mlp_W1[k*64+n]); }
  }
  ((u16x8*)pack)[t] = o;
}

// ---------------------------------------------------------------------------
// gather: ONE WAVE PER PATH. Loads unconditional (pipelined); masked-off
// loads redirect to the group's element-0 row (already fetched -> cache hit,
// no extra HBM). Masks applied as branchless float fma.
// Writes the 16-path tile image in bf16, pre-swizzled, in exact LDS layout.
// ---------------------------------------------------------------------------
__global__ __launch_bounds__(256) void gather_kernel(
    const int* __restrict__ paths,
    const int* __restrict__ pat_fp_idx,  const uint8_t* __restrict__ pat_fp_mask,
    const int* __restrict__ pat_ipc_idx, const uint8_t* __restrict__ pat_ipc_mask,
    const int* __restrict__ pat_comp_idx,const uint8_t* __restrict__ pat_comp_mask,
    const int* __restrict__ comp_ind_idx,const uint8_t* __restrict__ comp_ind_mask,
    const int* __restrict__ comp_pat_idx,const uint8_t* __restrict__ comp_pat_mask,
    const float* __restrict__ company_emb, const float* __restrict__ patent_emb,
    const float* __restrict__ fp_emb, const float* __restrict__ ipc_emb,
    const float* __restrict__ ind_emb,
    u16* __restrict__ tileimg, int P, int total)
{
  const int lane = threadIdx.x & 63;
  const int p = (blockIdx.x<<2) + (threadIdx.x>>6);
  if (p >= total) return;
  const int ps = p < P ? p : (P-1);
  const int4 pq = *(const int4*)&paths[ps*4];

  // ---- all indices + masks; masked-off -> group's element-0 index ----
  int4   ci  = *(const int4*)  &comp_ind_idx [pq.x*4];
  const uchar4 cim = *(const uchar4*)&comp_ind_mask[pq.x*4];
  ci.y = cim.y ? ci.y : ci.x;  ci.z = cim.z ? ci.z : ci.x;  ci.w = cim.w ? ci.w : ci.x;

  int4   cp[4]; uchar4 cpm[4];
  #pragma unroll
  for (int q=0;q<4;q++){
    cp[q]  = *(const int4*)  &comp_pat_idx [pq.x*16+q*4];
    cpm[q] = *(const uchar4*)&comp_pat_mask[pq.x*16+q*4];
  }
  const int cp0 = cp[0].x;
  #pragma unroll
  for (int q=0;q<4;q++){
    cp[q].x = cpm[q].x ? cp[q].x : cp0;  cp[q].y = cpm[q].y ? cp[q].y : cp0;
    cp[q].z = cpm[q].z ? cp[q].z : cp0;  cp[q].w = cpm[q].w ? cp[q].w : cp0;
  }

  int2   fi  = *(const int2*)  &pat_fp_idx  [pq.w*2];
  const uchar2 fim = *(const uchar2*)&pat_fp_mask [pq.w*2];
  fi.y = fim.y ? fi.y : fi.x;

  int2   ip[3]; uchar2 ipm[3];
  #pragma unroll
  for (int q=0;q<3;q++){
    ip[q]  = *(const int2*)  &pat_ipc_idx [pq.w*6+q*2];
    ipm[q] = *(const uchar2*)&pat_ipc_mask[pq.w*6+q*2];
  }
  const int ip0 = ip[0].x;
  #pragma unroll
  for (int q=0;q<3;q++){
    ip[q].x = ipm[q].x ? ip[q].x : ip0;  ip[q].y = ipm[q].y ? ip[q].y : ip0;
  }

  int2   cc  = *(const int2*)  &pat_comp_idx [pq.w*2];
  const uchar2 ccm = *(const uchar2*)&pat_comp_mask[pq.w*2];
  cc.y = ccm.y ? cc.y : cc.x;

  // ---- unconditional loads (independent; stay in flight together) ----
  const float e0 = company_emb[(long)pq.x*64+lane];
  const float e1 = patent_emb [(long)pq.y*64+lane];
  const float e2 = fp_emb     [(long)pq.z*64+lane];
  const float e3 = patent_emb [(long)pq.w*64+lane];

  float vind[4];
  vind[0]=ind_emb[(long)ci.x*64+lane]; vind[1]=ind_emb[(long)ci.y*64+lane];
  vind[2]=ind_emb[(long)ci.z*64+lane]; vind[3]=ind_emb[(long)ci.w*64+lane];
  float vpat[16];
  #pragma unroll
  for (int q=0;q<4;q++){
    vpat[q*4+0]=patent_emb[(long)cp[q].x*64+lane];
    vpat[q*4+1]=patent_emb[(long)cp[q].y*64+lane];
    vpat[q*4+2]=patent_emb[(long)cp[q].z*64+lane];
    vpat[q*4+3]=patent_emb[(long)cp[q].w*64+lane];
  }
  float vfp[2];
  vfp[0]=fp_emb[(long)fi.x*64+lane]; vfp[1]=fp_emb[(long)fi.y*64+lane];
  float vipc[6];
  #pragma unroll
  for (int q=0;q<3;q++){
    vipc[q*2+0]=ipc_emb[(long)ip[q].x*64+lane];
    vipc[q*2+1]=ipc_emb[(long)ip[q].y*64+lane];
  }
  float vcc[2];
  vcc[0]=company_emb[(long)cc.x*64+lane]; vcc[1]=company_emb[(long)cc.y*64+lane];

  // ---- branchless masked accumulate ----
  float mi[4] = {(float)cim.x,(float)cim.y,(float)cim.z,(float)cim.w};
  float mp[16];
  #pragma unroll
  for (int q=0;q<4;q++){ mp[q*4]=(float)cpm[q].x; mp[q*4+1]=(float)cpm[q].y; mp[q*4+2]=(float)cpm[q].z; mp[q*4+3]=(float)cpm[q].w; }
  float a0=0.f, a1=0.f, c0=0.f, c1=0.f;
  #pragma unroll
  for (int j=0;j<4;j++){ a0 = fmaf(mi[j], vind[j], a0); c0 += mi[j]; }
  #pragma unroll
  for (int j=0;j<16;j++){
    if (j&1){ a1 = fmaf(mp[j], vpat[j], a1); c1 += mp[j]; }
    else    { a0 = fmaf(mp[j], vpat[j], a0); c0 += mp[j]; }
  }
  const float csub = e0 + (a0+a1)/(c0+c1);

  float mf2[2] = {(float)fim.x,(float)fim.y};
  float mip[6];
  #pragma unroll
  for (int q=0;q<3;q++){ mip[q*2]=(float)ipm[q].x; mip[q*2+1]=(float)ipm[q].y; }
  float mcc[2] = {(float)ccm.x,(float)ccm.y};
  float b0=0.f, b1=0.f, d0=0.f, d1=0.f;
  #pragma unroll
  for (int j=0;j<2;j++){ b0 = fmaf(mf2[j], vfp[j], b0); d0 += mf2[j]; }
  #pragma unroll
  for (int j=0;j<6;j++){
    if (j&1){ b1 = fmaf(mip[j], vipc[j], b1); d1 += mip[j]; }
    else    { b0 = fmaf(mip[j], vipc[j], b0); d0 += mip[j]; }
  }
  #pragma unroll
  for (int j=0;j<2;j++){ b1 = fmaf(mcc[j], vcc[j], b1); d1 += mcc[j]; }
  const float psub = e3 + (b0+b1)/(d0+d1);

  const int tile = p>>4, r = p&15;
  const int sc = lane ^ ((r&7)<<3);
  u16* b = tileimg + ((size_t)tile*6*16 + r)*64 + sc;
  b[0*1024] = f2b(e0);   b[1*1024] = f2b(e1);   b[2*1024] = f2b(e2);
  b[3*1024] = f2b(e3);   b[4*1024] = f2b(csub); b[5*1024] = f2b(psub);
}

// ---------------------------------------------------------------------------
// compute: one wave per TWO 16-path tiles (B-fragment reuse: each 1 KiB
// B-frag load from the L2-resident pack feeds MFMAs for both tiles ->
// halves the L2 streaming that bound the previous version at ~18 us).
// LSTM is q-sliced (gates {q,4+q,8+q,12+q} at a time) to keep the live
// accumulator set at 32 VGPR (round-6 lesson: acc[16] = 64 VGPR + cap = spill).
// LDS: 2 x 6 tensors [16][64] bf16, XOR-swizzled halfcol ^= (row&7)<<3.
//   0:e0 1:e1 2:e2 3:e3 4:csub->h 5:psub
// ---------------------------------------------------------------------------
__global__ __launch_bounds__(64) void path_kernel_fast(
    const float* __restrict__ b_ih, const float* __restrict__ b_hh,
    const float* __restrict__ att_b1, const float* __restrict__ att_W2, const float* __restrict__ att_b2,
    const float* __restrict__ mlp_b1, const float* __restrict__ mlp_W2, const float* __restrict__ mlp_b2,
    const u16* __restrict__ pack, const u16* __restrict__ tileimg,
    float* __restrict__ out, int P, int tiles)
{
  __shared__ __align__(16) u16 ldsT[2][6][16][64];   // 24576 B
  __shared__ float wbuf[2][32];
  const int lane = threadIdx.x;
  const int t0 = blockIdx.x * 2;
  if (t0 >= tiles) return;
  const int t1s = (t0+1 < tiles) ? (t0+1) : t0;      // clamped source for loads
  const u16x8* pk8 = (const u16x8*)pack;

  // ---- stream both tile images (2 x 12288 B) straight into LDS ----
  const char* s0 = (const char*)(tileimg + (size_t)t0 *6144);
  const char* s1 = (const char*)(tileimg + (size_t)t1s*6144);
  #pragma unroll
  for (int it=0; it<12; ++it){
    __builtin_amdgcn_global_load_lds(
      (const __attribute__((address_space(1))) uint32_t*)(s0 + it*1024 + lane*16),
      (__attribute__((address_space(3))) uint32_t*)((char*)&ldsT[0][0][0][0] + it*1024),
      16, 0, 0);
  }
  #pragma unroll
  for (int it=0; it<12; ++it){
    __builtin_amdgcn_global_load_lds(
      (const __attribute__((address_space(1))) uint32_t*)(s1 + it*1024 + lane*16),
      (__attribute__((address_space(3))) uint32_t*)((char*)&ldsT[1][0][0][0] + it*1024),
      16, 0, 0);
  }
  asm volatile("s_waitcnt vmcnt(0)" ::: "memory");
  __builtin_amdgcn_sched_barrier(0);

  // A-frag loader: A[row = lane&15][k = ks*32 + (lane>>4)*8 + j]
  auto ldA = [&](int tl, int t, int ks)->s16x8{
    int row = lane & 15;
    int off = (ks*32 + ((lane>>4)<<3)) ^ ((row&7)<<3);
    return *(const s16x8*)&ldsT[tl][t][row][off];
  };

  // ---------------- attention fuse x2 ----------------
  float attb1v[4], attw2v[4];
  #pragma unroll
  for (int q=0;q<4;q++){ int c=(q<<4)+(lane&15); attb1v[q]=att_b1[c]; attw2v[q]=att_W2[c]; }
  const float attb2 = att_b2[0];

  auto fuse = [&](int st){
    s16x8 fe1[2][2], fe2[2][2], fs[2][2];
    #pragma unroll
    for (int tl=0; tl<2; ++tl)
      #pragma unroll
      for (int ks=0; ks<2; ++ks){
        fe1[tl][ks]=ldA(tl,1,ks); fe2[tl][ks]=ldA(tl,2,ks); fs[tl][ks]=ldA(tl,st,ks);
      }
    float t1[2][4], t2[2][4];
    #pragma unroll
    for (int tl=0; tl<2; ++tl)
      #pragma unroll
      for (int r=0;r<4;r++){ t1[tl][r]=0.f; t2[tl][r]=0.f; }
    #pragma unroll
    for (int nt=0; nt<4; ++nt){
      f32x4 x1[2], x2[2];
      #pragma unroll
      for (int tl=0; tl<2; ++tl){ x1[tl]=(f32x4){0.f,0.f,0.f,0.f}; x2[tl]=(f32x4){0.f,0.f,0.f,0.f}; }
      #pragma unroll
      for (int ks=0; ks<4; ++ks){
        s16x8 b = *(const s16x8*)&pk8[(nt*4+ks)*64 + lane];
        #pragma unroll
        for (int tl=0; tl<2; ++tl){
          s16x8 aa = (ks<2) ? fe1[tl][ks] : fs[tl][ks-2];
          s16x8 bb = (ks<2) ? fe2[tl][ks] : fs[tl][ks-2];
          x1[tl] = mf(aa, b, x1[tl]);
          x2[tl] = mf(bb, b, x2[tl]);
        }
      }
      #pragma unroll
      for (int tl=0; tl<2; ++tl)
        #pragma unroll
        for (int r=0;r<4;r++){
          float h1=x1[tl][r]+attb1v[nt]; h1 = h1>0.f?h1:0.2f*h1;
          float h2=x2[tl][r]+attb1v[nt]; h2 = h2>0.f?h2:0.2f*h2;
          t1[tl][r] += h1*attw2v[nt]; t2[tl][r] += h2*attw2v[nt];
        }
    }
    #pragma unroll
    for (int tl=0; tl<2; ++tl)
      #pragma unroll
      for (int r=0;r<4;r++){
        #pragma unroll
        for (int off=1; off<16; off<<=1){
          t1[tl][r]+=__shfl_xor(t1[tl][r],off,64);
          t2[tl][r]+=__shfl_xor(t2[tl][r],off,64);
        }
      }
    if ((lane&15)==0){
      int g = lane>>4;
      #pragma unroll
      for (int tl=0; tl<2; ++tl)
        #pragma unroll
        for (int r=0;r<4;r++){
          wbuf[tl][g*4+r] = sigm(t1[tl][r]+attb2);
          wbuf[tl][16+g*4+r] = sigm(t2[tl][r]+attb2);
        }
    }
    // e1/e2 += sub * w[row]
    #pragma unroll
    for (int tl=0; tl<2; ++tl)
      #pragma unroll
      for (int it=0; it<2; it++){
        int row = it*8 + (lane>>3);
        int off = ((lane&7)<<3) ^ ((row&7)<<3);
        u16x8 ue1 = *(const u16x8*)&ldsT[tl][1][row][off];
        u16x8 ue2 = *(const u16x8*)&ldsT[tl][2][row][off];
        u16x8 us  = *(const u16x8*)&ldsT[tl][st][row][off];
        float wA = wbuf[tl][row], wB = wbuf[tl][16+row];
        u16x8 o1, o2;
        #pragma unroll
        for (int j=0;j<8;j++){
          float sv=b2f(us[j]);
          o1[j]=f2b(b2f(ue1[j]) + sv*wA);
          o2[j]=f2b(b2f(ue2[j]) + sv*wB);
        }
        *(u16x8*)&ldsT[tl][1][row][off]=o1;
        *(u16x8*)&ldsT[tl][2][row][off]=o2;
      }
  };
  fuse(4);   // csub
  fuse(5);   // psub

  // ---------------- LSTM (h in slot 4; q-sliced gates keep acc at 32 VGPR) --
  float biasv[16];
  #pragma unroll
  for (int nt=0;nt<16;nt++){ int c=(nt<<4)+(lane&15); biasv[nt]=b_ih[c]+b_hh[c]; }
  float cst[2][16];
  #pragma unroll
  for (int tl=0; tl<2; ++tl)
    #pragma unroll
    for (int i=0;i<16;i++) cst[tl][i]=0.f;

  auto step=[&](int xt, bool useH){
    s16x8 fx[2][2], fh[2][2];
    #pragma unroll
    for (int tl=0; tl<2; ++tl){
      fx[tl][0]=ldA(tl,xt,0); fx[tl][1]=ldA(tl,xt,1);
      if (useH){ fh[tl][0]=ldA(tl,4,0); fh[tl][1]=ldA(tl,4,1); }
    }
    #pragma unroll
    for (int q=0;q<4;q++){
      f32x4 acc[2][4];
      #pragma unroll
      for (int tl=0; tl<2; ++tl)
        #pragma unroll
        for (int g=0; g<4; ++g) acc[tl][g]=(f32x4){0.f,0.f,0.f,0.f};
      #pragma unroll
      for (int g=0; g<4; ++g){
        int nt = g*4+q;
        s16x8 b0 = *(const s16x8*)&pk8[1024 + (nt*2+0)*64 + lane];
        s16x8 b1 = *(const s16x8*)&pk8[1024 + (nt*2+1)*64 + lane];
        #pragma unroll
        for (int tl=0; tl<2; ++tl){
          acc[tl][g] = mf(fx[tl][0], b0, acc[tl][g]);
          acc[tl][g] = mf(fx[tl][1], b1, acc[tl][g]);
        }
        if (useH){
          s16x8 b2 = *(const s16x8*)&pk8[3072 + (nt*2+0)*64 + lane];
          s16x8 b3 = *(const s16x8*)&pk8[3072 + (nt*2+1)*64 + lane];
          #pragma unroll
          for (int tl=0; tl<2; ++tl){
            acc[tl][g] = mf(fh[tl][0], b2, acc[tl][g]);
            acc[tl][g] = mf(fh[tl][1], b3, acc[tl][g]);
          }
        }
      }
      #pragma unroll
      for (int tl=0; tl<2; ++tl)
        #pragma unroll
        for (int r=0;r<4;r++){
          float iv=sigm  (acc[tl][0][r]+biasv[q]);
          float fv=sigm  (acc[tl][1][r]+biasv[4+q]);
          float gv=tanhf_(acc[tl][2][r]+biasv[8+q]);
          float ov=sigm  (acc[tl][3][r]+biasv[12+q]);
          float ccv=fv*cst[tl][q*4+r]+iv*gv;
          cst[tl][q*4+r]=ccv;
          float hv=ov*tanhf_(ccv);
          int row=((lane>>4)<<2)+r;
          int col=(lane&15)+(q<<4);
          ldsT[tl][4][row][col ^ ((row&7)<<3)] = f2b(hv);
        }
    }
  };
  step(0,false); step(1,true); step(2,true); step(3,true);

  // ---------------- MLP head ----------------
  float mlb1v[4], mlw2v[4];
  #pragma unroll
  for (int q=0;q<4;q++){ int c=(q<<4)+(lane&15); mlb1v[q]=mlp_b1[c]; mlw2v[q]=mlp_W2[c]; }
  const float mlb2 = mlp_b2[0];
  s16x8 gh[2][2];
  #pragma unroll
  for (int tl=0; tl<2; ++tl){ gh[tl][0]=ldA(tl,4,0); gh[tl][1]=ldA(tl,4,1); }
  float tt[2][4];
  #pragma unroll
  for (int tl=0; tl<2; ++tl)
    #pragma unroll
    for (int r=0;r<4;r++) tt[tl][r]=0.f;
  #pragma unroll
  for (int nt=0;nt<4;nt++){
    s16x8 b0 = *(const s16x8*)&pk8[5120 + (nt*2+0)*64 + lane];
    s16x8 b1 = *(const s16x8*)&pk8[5120 + (nt*2+1)*64 + lane];
    #pragma unroll
    for (int tl=0; tl<2; ++tl){
      f32x4 a={0.f,0.f,0.f,0.f};
      a = mf(gh[tl][0], b0, a);
      a = mf(gh[tl][1], b1, a);
      #pragma unroll
      for (int r=0;r<4;r++){ float mv=a[r]+mlb1v[nt]; mv=mv>0.f?mv:0.f; tt[tl][r]+=mv*mlw2v[nt]; }
    }
  }
  #pragma unroll
  for (int tl=0; tl<2; ++tl)
    #pragma unroll
    for (int r=0;r<4;r++){
      #pragma unroll
      for (int off=1; off<16; off<<=1) tt[tl][r]+=__shfl_xor(tt[tl][r],off,64);
    }
  if ((lane&15)==0){
    #pragma unroll
    for (int tl=0; tl<2; ++tl){
      int base = (t0+tl)*16;
      #pragma unroll
      for (int r=0;r<4;r++){
        int p = base + ((lane>>4)<<2) + r;
        if (p < P) out[p] = sigm(tt[tl][r]+mlb2);
      }
    }
  }
}

// ---------------------------------------------------------------------------
// fallback fused kernel if ws_size is too small
// ---------------------------------------------------------------------------
__global__ __launch_bounds__(64) void path_kernel_fused(
    const int* __restrict__ paths,
    const int* __restrict__ pat_fp_idx,  const uint8_t* __restrict__ pat_fp_mask,
    const int* __restrict__ pat_ipc_idx, const uint8_t* __restrict__ pat_ipc_mask,
    const int* __restrict__ pat_comp_idx,const uint8_t* __restrict__ pat_comp_mask,
    const int* __restrict__ comp_ind_idx,const uint8_t* __restrict__ comp_ind_mask,
    const int* __restrict__ comp_pat_idx,const uint8_t* __restrict__ comp_pat_mask,
    const float* __restrict__ company_emb, const float* __restrict__ patent_emb,
    const float* __restrict__ fp_emb, const float* __restrict__ ipc_emb,
    const float* __restrict__ ind_emb,
    const float* __restrict__ b_ih, const float* __restrict__ b_hh,
    const float* __restrict__ att_b1, const float* __restrict__ att_W2, const float* __restrict__ att_b2,
    const float* __restrict__ mlp_b1, const float* __restrict__ mlp_W2, const float* __restrict__ mlp_b2,
    const u16* __restrict__ pack,
    float* __restrict__ out, int P)
{
  __shared__ __align__(16) u16 ldsT[7][16][64];
  __shared__ float wbuf[32];
  const int lane = threadIdx.x;
  const int base = blockIdx.x * 16;
  if (base >= P) return;
  const u16x8* pk8 = (const u16x8*)pack;

  #pragma unroll 2
  for (int r=0;r<16;r++){
    int p = base + r; int ps = p < P ? p : (P-1);
    const int4 pq = *(const int4*)&paths[ps*4];
    float e0 = company_emb[(long)pq.x*64+lane];
    float e1 = patent_emb [(long)pq.y*64+lane];
    float e2 = fp_emb     [(long)pq.z*64+lane];
    float e3 = patent_emb [(long)pq.w*64+lane];
    float acc=0.f, cnt=0.f;
    #pragma unroll
    for (int jj=0;jj<4;jj++)
      if (comp_ind_mask[pq.x*4+jj]) { acc += ind_emb[(long)comp_ind_idx[pq.x*4+jj]*64+lane]; cnt += 1.f; }
    #pragma unroll
    for (int jj=0;jj<16;jj++)
      if (comp_pat_mask[pq.x*16+jj]){ acc += patent_emb[(long)comp_pat_idx[pq.x*16+jj]*64+lane]; cnt += 1.f; }
    float csub = e0 + acc/cnt;
    acc=0.f; cnt=0.f;
    #pragma unroll
    for (int jj=0;jj<2;jj++)
      if (pat_fp_mask[pq.w*2+jj])  { acc += fp_emb[(long)pat_fp_idx[pq.w*2+jj]*64+lane]; cnt += 1.f; }
    #pragma unroll
    for (int jj=0;jj<6;jj++)
      if (pat_ipc_mask[pq.w*6+jj]) { acc += ipc_emb[(long)pat_ipc_idx[pq.w*6+jj]*64+lane]; cnt += 1.f; }
    #pragma unroll
    for (int jj=0;jj<2;jj++)
      if (pat_comp_mask[pq.w*2+jj]){ acc += company_emb[(long)pat_comp_idx[pq.w*2+jj]*64+lane]; cnt += 1.f; }
    float psub = e3 + acc/cnt;
    int sc = lane ^ ((r&7)<<3);
    ldsT[0][r][sc]=f2b(e0); ldsT[1][r][sc]=f2b(e1); ldsT[2][r][sc]=f2b(e2);
    ldsT[3][r][sc]=f2b(e3); ldsT[4][r][sc]=f2b(csub); ldsT[5][r][sc]=f2b(psub);
  }

  auto ldA = [&](int t, int ks)->s16x8{
    int row = lane & 15;
    int off = (ks*32 + ((lane>>4)<<3)) ^ ((row&7)<<3);
    return *(const s16x8*)&ldsT[t][row][off];
  };

  float attb1v[4], attw2v[4];
  #pragma unroll
  for (int q=0;q<4;q++){ int c=(q<<4)+(lane&15); attb1v[q]=att_b1[c]; attw2v[q]=att_W2[c]; }
  const float attb2 = att_b2[0];

  auto fuse = [&](int st){
    s16x8 a1[4], a2[4];
    #pragma unroll
    for (int ks=0;ks<2;ks++){
      a1[ks]=ldA(1,ks); a2[ks]=ldA(2,ks);
      s16x8 asub=ldA(st,ks); a1[2+ks]=asub; a2[2+ks]=asub;
    }
    f32x4 c1[4], c2[4];
    #pragma unroll
    for (int nt=0;nt<4;nt++){
      f32x4 x1={0.f,0.f,0.f,0.f}, x2={0.f,0.f,0.f,0.f};
      #pragma unroll
      for (int ks=0;ks<4;ks++){
        s16x8 b = *(const s16x8*)&pk8[(nt*4+ks)*64 + lane];
        x1 = mf(a1[ks], b, x1);
        x2 = mf(a2[ks], b, x2);
      }
      c1[nt]=x1; c2[nt]=x2;
    }
    float t1[4]={0.f,0.f,0.f,0.f}, t2[4]={0.f,0.f,0.f,0.f};
    #pragma unroll
    for (int nt=0;nt<4;nt++){
      #pragma unroll
      for (int r=0;r<4;r++){
        float h1=c1[nt][r]+attb1v[nt]; h1 = h1>0.f?h1:0.2f*h1;
        float h2=c2[nt][r]+attb1v[nt]; h2 = h2>0.f?h2:0.2f*h2;
        t1[r] += h1*attw2v[nt]; t2[r] += h2*attw2v[nt];
      }
    }
    #pragma unroll
    for (int r=0;r<4;r++){
      #pragma unroll
      for (int off=1; off<16; off<<=1){ t1[r]+=__shfl_xor(t1[r],off,64); t2[r]+=__shfl_xor(t2[r],off,64); }
    }
    if ((lane&15)==0){
      int g = lane>>4;
      #pragma unroll
      for (int r=0;r<4;r++){ wbuf[g*4+r] = sigm(t1[r]+attb2); wbuf[16+g*4+r] = sigm(t2[r]+attb2); }
    }
    #pragma unroll
    for (int it=0; it<2; it++){
      int row = it*8 + (lane>>3);
      int off = ((lane&7)<<3) ^ ((row&7)<<3);
      u16x8 ue1 = *(const u16x8*)&ldsT[1][row][off];
      u16x8 ue2 = *(const u16x8*)&ldsT[2][row][off];
      u16x8 us  = *(const u16x8*)&ldsT[st][row][off];
      float wA = wbuf[row], wB = wbuf[16+row];
      u16x8 o1, o2;
      #pragma unroll
      for (int j=0;j<8;j++){
        float sv=b2f(us[j]);
        o1[j]=f2b(b2f(ue1[j]) + sv*wA);
        o2[j]=f2b(b2f(ue2[j]) + sv*wB);
      }
      *(u16x8*)&ldsT[1][row][off]=o1;
      *(u16x8*)&ldsT[2][row][off]=o2;
    }
  };
  fuse(4); fuse(5);

  float biasv[16];
  #pragma unroll
  for (int nt=0;nt<16;nt++){ int c=(nt<<4)+(lane&15); biasv[nt]=b_ih[c]+b_hh[c]; }
  float cst[16];
  #pragma unroll
  for (int i=0;i<16;i++) cst[i]=0.f;

  auto step=[&](int xt, bool useH){
    s16x8 ax0=ldA(xt,0), ax1=ldA(xt,1);
    s16x8 ah0, ah1;
    if (useH){ ah0=ldA(6,0); ah1=ldA(6,1); }
    f32x4 acc[16];
    #pragma unroll
    for (int nt=0;nt<16;nt++){
      f32x4 a={0.f,0.f,0.f,0.f};
      a = mf(ax0, *(const s16x8*)&pk8[1024 + (nt*2+0)*64 + lane], a);
      a = mf(ax1, *(const s16x8*)&pk8[1024 + (nt*2+1)*64 + lane], a);
      if (useH){
        a = mf(ah0, *(const s16x8*)&pk8[3072 + (nt*2+0)*64 + lane], a);
        a = mf(ah1, *(const s16x8*)&pk8[3072 + (nt*2+1)*64 + lane], a);
      }
      acc[nt]=a;
    }
    #pragma unroll
    for (int q=0;q<4;q++){
      #pragma unroll
      for (int r=0;r<4;r++){
        float iv=sigm  (acc[q    ][r]+biasv[q]);
        float fv=sigm  (acc[4+q  ][r]+biasv[4+q]);
        float gv=tanhf_(acc[8+q  ][r]+biasv[8+q]);
        float ov=sigm  (acc[12+q ][r]+biasv[12+q]);
        float cc=fv*cst[q*4+r]+iv*gv;
        cst[q*4+r]=cc;
        float hv=ov*tanhf_(cc);
        int row=((lane>>4)<<2)+r;
        int col=(lane&15)+(q<<4);
        ldsT[6][row][col ^ ((row&7)<<3)] = f2b(hv);
      }
    }
  };
  step(0,false); step(1,true); step(2,true); step(3,true);

  float mlb1v[4], mlw2v[4];
  #pragma unroll
  for (int q=0;q<4;q++){ int c=(q<<4)+(lane&15); mlb1v[q]=mlp_b1[c]; mlw2v[q]=mlp_W2[c]; }
  const float mlb2 = mlp_b2[0];
  s16x8 ah0=ldA(6,0), ah1=ldA(6,1);
  f32x4 mac[4];
  #pragma unroll
  for (int nt=0;nt<4;nt++){
    f32x4 a={0.f,0.f,0.f,0.f};
    a = mf(ah0, *(const s16x8*)&pk8[5120 + (nt*2+0)*64 + lane], a);
    a = mf(ah1, *(const s16x8*)&pk8[5120 + (nt*2+1)*64 + lane], a);
    mac[nt]=a;
  }
  float tt[4]={0.f,0.f,0.f,0.f};
  #pragma unroll
  for (int nt=0;nt<4;nt++){
    #pragma unroll
    for (int r=0;r<4;r++){ float mv=mac[nt][r]+mlb1v[nt]; mv=mv>0.f?mv:0.f; tt[r]+=mv*mlw2v[nt]; }
  }
  #pragma unroll
  for (int r=0;r<4;r++){
    #pragma unroll
    for (int off=1; off<16; off<<=1) tt[r]+=__shfl_xor(tt[r],off,64);
  }
  if ((lane&15)==0){
    #pragma unroll
    for (int r=0;r<4;r++){
      int p = base + ((lane>>4)<<2) + r;
      if (p < P) out[p] = sigm(tt[r]+mlb2);
    }
  }
}

extern "C" void kernel_launch(void* const* d_in, const int* in_sizes, int n_in,
                              void* d_out, int out_size, void* d_ws, size_t ws_size,
                              hipStream_t stream){
  const int*     paths         = (const int*)    d_in[0];
  const int*     pat_fp_idx    = (const int*)    d_in[2];
  const uint8_t* pat_fp_mask   = (const uint8_t*)d_in[3];
  const int*     pat_ipc_idx   = (const int*)    d_in[4];
  const uint8_t* pat_ipc_mask  = (const uint8_t*)d_in[5];
  const int*     pat_comp_idx  = (const int*)    d_in[6];
  const uint8_t* pat_comp_mask = (const uint8_t*)d_in[7];
  const int*     comp_ind_idx  = (const int*)    d_in[8];
  const uint8_t* comp_ind_mask = (const uint8_t*)d_in[9];
  const int*     comp_pat_idx  = (const int*)    d_in[10];
  const uint8_t* comp_pat_mask = (const uint8_t*)d_in[11];
  const float*   company_emb   = (const float*)  d_in[12];
  const float*   patent_emb    = (const float*)  d_in[13];
  const float*   fp_emb        = (const float*)  d_in[14];
  const float*   ipc_emb       = (const float*)  d_in[15];
  const float*   ind_emb       = (const float*)  d_in[16];
  const float*   W_ih          = (const float*)  d_in[17];
  const float*   W_hh          = (const float*)  d_in[18];
  const float*   b_ih          = (const float*)  d_in[19];
  const float*   b_hh          = (const float*)  d_in[20];
  const float*   att_W1        = (const float*)  d_in[21];
  const float*   att_b1        = (const float*)  d_in[22];
  const float*   att_W2        = (const float*)  d_in[23];
  const float*   att_b2        = (const float*)  d_in[24];
  const float*   mlp_W1        = (const float*)  d_in[25];
  const float*   mlp_b1        = (const float*)  d_in[26];
  const float*   mlp_W2        = (const float*)  d_in[27];
  const float*   mlp_b2        = (const float*)  d_in[28];
  float* out = (float*)d_out;
  const int P = in_sizes[1];

  u16* pack = (u16*)d_ws;                       // 90112 B
  const size_t packB = 5632u * 16u;
  const int tiles = (P + 15) / 16;
  const int total = tiles * 16;
  const size_t need = packB + (size_t)tiles * 12288u;

  prep_kernel<<<22, 256, 0, stream>>>(att_W1, W_ih, W_hh, mlp_W1, pack);

  if (ws_size >= need){
    u16* tileimg = (u16*)((char*)d_ws + packB);
    gather_kernel<<<tiles*4, 256, 0, stream>>>(
        paths,
        pat_fp_idx, pat_fp_mask, pat_ipc_idx, pat_ipc_mask, pat_comp_idx, pat_comp_mask,
        comp_ind_idx, comp_ind_mask, comp_pat_idx, comp_pat_mask,
        company_emb, patent_emb, fp_emb, ipc_emb, ind_emb,
        tileimg, P, total);
    int blocks2 = (tiles + 1) / 2;
    path_kernel_fast<<<blocks2, 64, 0, stream>>>(
        b_ih, b_hh, att_b1, att_W2, att_b2,
        mlp_b1, mlp_W2, mlp_b2,
        pack, tileimg, out, P, tiles);
  } else {
    path_kernel_fused<<<tiles, 64, 0, stream>>>(
        paths,
        pat_fp_idx, pat_fp_mask, pat_ipc_idx, pat_ipc_mask, pat_comp_idx, pat_comp_mask,
        comp_ind_idx, comp_ind_mask, comp_pat_idx, comp_pat_mask,
        company_emb, patent_emb, fp_emb, ipc_emb, ind_emb,
        b_ih, b_hh, att_b1, att_W2, att_b2,
        mlp_b1, mlp_W2, mlp_b2,
        pack, out, P);
  }
}

// Round 9
// 69.320 us; speedup vs baseline: 1.4466x; 1.4466x over previous
//
#include <hip/hip_runtime.h>
#include <stdint.h>

typedef unsigned short u16;
typedef unsigned short u16x8 __attribute__((ext_vector_type(8)));
typedef short s16x8 __attribute__((ext_vector_type(8)));
typedef float f32x4 __attribute__((ext_vector_type(4)));

__device__ __forceinline__ float b2f(u16 u){ return __uint_as_float(((unsigned)u)<<16); }
__device__ __forceinline__ u16 f2b(float f){
  unsigned u = __float_as_uint(f);
  u += 0x7FFF + ((u>>16)&1);            // round-to-nearest-even
  return (u16)(u>>16);
}
__device__ __forceinline__ float sigm(float x){ return 1.0f/(1.0f+__expf(-x)); }
__device__ __forceinline__ float tanhf_(float x){ return 2.0f/(1.0f+__expf(-2.0f*x)) - 1.0f; }

__device__ __forceinline__ f32x4 mf(s16x8 a, s16x8 b, f32x4 c){
  return __builtin_amdgcn_mfma_f32_16x16x32_bf16(a, b, c, 0, 0, 0);
}

// Shared prep body: pack weights into exact bf16 B-fragment order.
//   frag layout: lane holds B[k = ks*32 + (lane>>4)*8 + j][n = nt*16 + (lane&15)], j=0..7
//   pack8[] regions (u16x8 index): att_W1 [0,1024), W_ih^T [1024,3072),
//                                  W_hh^T [3072,5120), mlp_W1 [5120,5632)
__device__ __forceinline__ void prep_body(int t,
    const float* __restrict__ att_W1, const float* __restrict__ W_ih,
    const float* __restrict__ W_hh, const float* __restrict__ mlp_W1,
    u16* __restrict__ pack){
  int lane = t & 63;
  int kb = (lane>>4)<<3;
  int nl = lane & 15;
  u16x8 o;
  if (t < 1024){
    int f = t>>6; int nt=f>>2, ks=f&3;
    int n = (nt<<4)+nl;
    #pragma unroll
    for (int j=0;j<8;j++){ int k = ks*32+kb+j; o[j] = f2b(att_W1[k*64+n]); }
  } else if (t < 3072){
    int f=(t-1024)>>6; int nt=f>>1, ks=f&1;
    int n=(nt<<4)+nl;
    #pragma unroll
    for (int j=0;j<8;j++){ int k=ks*32+kb+j; o[j]=f2b(W_ih[n*64+k]); }   // B = W_ih^T
  } else if (t < 5120){
    int f=(t-3072)>>6; int nt=f>>1, ks=f&1;
    int n=(nt<<4)+nl;
    #pragma unroll
    for (int j=0;j<8;j++){ int k=ks*32+kb+j; o[j]=f2b(W_hh[n*64+k]); }   // B = W_hh^T
  } else {
    int f=(t-5120)>>6; int nt=f>>1, ks=f&1;
    int n=(nt<<4)+nl;
    #pragma unroll
    for (int j=0;j<8;j++){ int k=ks*32+kb+j; o[j]=f2b(mlp_W1[k*64+n]); }
  }
  ((u16x8*)pack)[t] = o;
}

__global__ void prep_kernel(const float* __restrict__ att_W1, const float* __restrict__ W_ih,
                            const float* __restrict__ W_hh, const float* __restrict__ mlp_W1,
                            u16* __restrict__ pack){
  int t = blockIdx.x*blockDim.x + threadIdx.x;
  if (t >= 5632) return;
  prep_body(t, att_W1, W_ih, W_hh, mlp_W1, pack);
}

// ---------------------------------------------------------------------------
// gather: ONE WAVE PER PATH. Loads unconditional (pipelined); masked-off
// loads redirect to the group's element-0 row (cache hit, no extra HBM).
// First 22 blocks ALSO run the prep body (pack consumed only by the next
// kernel -> no sync needed); saves a separate prep launch.
// Writes the 16-path tile image in bf16, pre-swizzled, in exact LDS layout.
// ---------------------------------------------------------------------------
__global__ __launch_bounds__(256) void gather_kernel(
    const int* __restrict__ paths,
    const int* __restrict__ pat_fp_idx,  const uint8_t* __restrict__ pat_fp_mask,
    const int* __restrict__ pat_ipc_idx, const uint8_t* __restrict__ pat_ipc_mask,
    const int* __restrict__ pat_comp_idx,const uint8_t* __restrict__ pat_comp_mask,
    const int* __restrict__ comp_ind_idx,const uint8_t* __restrict__ comp_ind_mask,
    const int* __restrict__ comp_pat_idx,const uint8_t* __restrict__ comp_pat_mask,
    const float* __restrict__ company_emb, const float* __restrict__ patent_emb,
    const float* __restrict__ fp_emb, const float* __restrict__ ipc_emb,
    const float* __restrict__ ind_emb,
    const float* __restrict__ att_W1, const float* __restrict__ W_ih,
    const float* __restrict__ W_hh, const float* __restrict__ mlp_W1,
    u16* __restrict__ pack,
    u16* __restrict__ tileimg, int P, int total)
{
  {
    int t = blockIdx.x*256 + threadIdx.x;
    if (t < 5632) prep_body(t, att_W1, W_ih, W_hh, mlp_W1, pack);
  }

  const int lane = threadIdx.x & 63;
  const int p = (blockIdx.x<<2) + (threadIdx.x>>6);
  if (p >= total) return;
  const int ps = p < P ? p : (P-1);
  const int4 pq = *(const int4*)&paths[ps*4];

  // ---- all indices + masks; masked-off -> group's element-0 index ----
  int4   ci  = *(const int4*)  &comp_ind_idx [pq.x*4];
  const uchar4 cim = *(const uchar4*)&comp_ind_mask[pq.x*4];
  ci.y = cim.y ? ci.y : ci.x;  ci.z = cim.z ? ci.z : ci.x;  ci.w = cim.w ? ci.w : ci.x;

  int4   cp[4]; uchar4 cpm[4];
  #pragma unroll
  for (int q=0;q<4;q++){
    cp[q]  = *(const int4*)  &comp_pat_idx [pq.x*16+q*4];
    cpm[q] = *(const uchar4*)&comp_pat_mask[pq.x*16+q*4];
  }
  const int cp0 = cp[0].x;
  #pragma unroll
  for (int q=0;q<4;q++){
    cp[q].x = cpm[q].x ? cp[q].x : cp0;  cp[q].y = cpm[q].y ? cp[q].y : cp0;
    cp[q].z = cpm[q].z ? cp[q].z : cp0;  cp[q].w = cpm[q].w ? cp[q].w : cp0;
  }

  int2   fi  = *(const int2*)  &pat_fp_idx  [pq.w*2];
  const uchar2 fim = *(const uchar2*)&pat_fp_mask [pq.w*2];
  fi.y = fim.y ? fi.y : fi.x;

  int2   ip[3]; uchar2 ipm[3];
  #pragma unroll
  for (int q=0;q<3;q++){
    ip[q]  = *(const int2*)  &pat_ipc_idx [pq.w*6+q*2];
    ipm[q] = *(const uchar2*)&pat_ipc_mask[pq.w*6+q*2];
  }
  const int ip0 = ip[0].x;
  #pragma unroll
  for (int q=0;q<3;q++){
    ip[q].x = ipm[q].x ? ip[q].x : ip0;  ip[q].y = ipm[q].y ? ip[q].y : ip0;
  }

  int2   cc  = *(const int2*)  &pat_comp_idx [pq.w*2];
  const uchar2 ccm = *(const uchar2*)&pat_comp_mask[pq.w*2];
  cc.y = ccm.y ? cc.y : cc.x;

  // ---- unconditional loads (independent; stay in flight together) ----
  const float e0 = company_emb[(long)pq.x*64+lane];
  const float e1 = patent_emb [(long)pq.y*64+lane];
  const float e2 = fp_emb     [(long)pq.z*64+lane];
  const float e3 = patent_emb [(long)pq.w*64+lane];

  float vind[4];
  vind[0]=ind_emb[(long)ci.x*64+lane]; vind[1]=ind_emb[(long)ci.y*64+lane];
  vind[2]=ind_emb[(long)ci.z*64+lane]; vind[3]=ind_emb[(long)ci.w*64+lane];
  float vpat[16];
  #pragma unroll
  for (int q=0;q<4;q++){
    vpat[q*4+0]=patent_emb[(long)cp[q].x*64+lane];
    vpat[q*4+1]=patent_emb[(long)cp[q].y*64+lane];
    vpat[q*4+2]=patent_emb[(long)cp[q].z*64+lane];
    vpat[q*4+3]=patent_emb[(long)cp[q].w*64+lane];
  }
  float vfp[2];
  vfp[0]=fp_emb[(long)fi.x*64+lane]; vfp[1]=fp_emb[(long)fi.y*64+lane];
  float vipc[6];
  #pragma unroll
  for (int q=0;q<3;q++){
    vipc[q*2+0]=ipc_emb[(long)ip[q].x*64+lane];
    vipc[q*2+1]=ipc_emb[(long)ip[q].y*64+lane];
  }
  float vcc[2];
  vcc[0]=company_emb[(long)cc.x*64+lane]; vcc[1]=company_emb[(long)cc.y*64+lane];

  // ---- branchless masked accumulate ----
  float mi[4] = {(float)cim.x,(float)cim.y,(float)cim.z,(float)cim.w};
  float mp[16];
  #pragma unroll
  for (int q=0;q<4;q++){ mp[q*4]=(float)cpm[q].x; mp[q*4+1]=(float)cpm[q].y; mp[q*4+2]=(float)cpm[q].z; mp[q*4+3]=(float)cpm[q].w; }
  float a0=0.f, a1=0.f, c0=0.f, c1=0.f;
  #pragma unroll
  for (int j=0;j<4;j++){ a0 = fmaf(mi[j], vind[j], a0); c0 += mi[j]; }
  #pragma unroll
  for (int j=0;j<16;j++){
    if (j&1){ a1 = fmaf(mp[j], vpat[j], a1); c1 += mp[j]; }
    else    { a0 = fmaf(mp[j], vpat[j], a0); c0 += mp[j]; }
  }
  const float csub = e0 + (a0+a1)/(c0+c1);

  float mf2[2] = {(float)fim.x,(float)fim.y};
  float mip[6];
  #pragma unroll
  for (int q=0;q<3;q++){ mip[q*2]=(float)ipm[q].x; mip[q*2+1]=(float)ipm[q].y; }
  float mcc[2] = {(float)ccm.x,(float)ccm.y};
  float b0=0.f, b1=0.f, d0=0.f, d1=0.f;
  #pragma unroll
  for (int j=0;j<2;j++){ b0 = fmaf(mf2[j], vfp[j], b0); d0 += mf2[j]; }
  #pragma unroll
  for (int j=0;j<6;j++){
    if (j&1){ b1 = fmaf(mip[j], vipc[j], b1); d1 += mip[j]; }
    else    { b0 = fmaf(mip[j], vipc[j], b0); d0 += mip[j]; }
  }
  #pragma unroll
  for (int j=0;j<2;j++){ b1 = fmaf(mcc[j], vcc[j], b1); d1 += mcc[j]; }
  const float psub = e3 + (b0+b1)/(d0+d1);

  const int tile = p>>4, r = p&15;
  const int sc = lane ^ ((r&7)<<3);
  u16* b = tileimg + ((size_t)tile*6*16 + r)*64 + sc;
  b[0*1024] = f2b(e0);   b[1*1024] = f2b(e1);   b[2*1024] = f2b(e2);
  b[3*1024] = f2b(e3);   b[4*1024] = f2b(csub); b[5*1024] = f2b(psub);
}

// ---------------------------------------------------------------------------
// compute (R7 known-good config): one wave per 16-path tile (2048 blocks x
// 64 thr -> 8 waves/CU, enough TLP to stream B-frags from the L2-resident
// pack at ~30 TB/s). Tile image -> LDS via global_load_lds, then MFMA
// pipeline. No __syncthreads.
// LDS: 6 tensors [16][64] bf16, XOR-swizzled halfcol ^= (row&7)<<3.
//   0:e0 1:e1 2:e2 3:e3 4:csub->h 5:psub   (h reuses slot 4 after fuse)
// R6 lesson: do NOT cap VGPR (needs ~120; cap => acc spills to scratch, 5x).
// R8 lesson: do NOT batch 2 tiles/wave (grid halves -> 4 waves/CU -> 3.4x).
// ---------------------------------------------------------------------------
__global__ __launch_bounds__(64) void path_kernel_fast(
    const float* __restrict__ b_ih, const float* __restrict__ b_hh,
    const float* __restrict__ att_b1, const float* __restrict__ att_W2, const float* __restrict__ att_b2,
    const float* __restrict__ mlp_b1, const float* __restrict__ mlp_W2, const float* __restrict__ mlp_b2,
    const u16* __restrict__ pack, const u16* __restrict__ tileimg,
    float* __restrict__ out, int P)
{
  __shared__ __align__(16) u16 ldsT[6][16][64];   // 12288 B
  __shared__ float wbuf[32];
  const int lane = threadIdx.x;
  const int tile = blockIdx.x;
  const int base = tile * 16;
  if (base >= P) return;
  const u16x8* pk8 = (const u16x8*)pack;

  // ---- stream tile image (12288 B) straight into LDS ----
  const char* src = (const char*)(tileimg + (size_t)tile*6144);
  #pragma unroll
  for (int it=0; it<12; ++it){
    __builtin_amdgcn_global_load_lds(
      (const __attribute__((address_space(1))) uint32_t*)(src + it*1024 + lane*16),
      (__attribute__((address_space(3))) uint32_t*)((char*)&ldsT[0][0][0] + it*1024),
      16, 0, 0);
  }
  asm volatile("s_waitcnt vmcnt(0)" ::: "memory");
  __builtin_amdgcn_sched_barrier(0);

  // A-frag loader: A[row = lane&15][k = ks*32 + (lane>>4)*8 + j]
  auto ldA = [&](int t, int ks)->s16x8{
    int row = lane & 15;
    int off = (ks*32 + ((lane>>4)<<3)) ^ ((row&7)<<3);
    return *(const s16x8*)&ldsT[t][row][off];
  };

  // ---------------- attention fuse x2 ----------------
  float attb1v[4], attw2v[4];
  #pragma unroll
  for (int q=0;q<4;q++){ int c=(q<<4)+(lane&15); attb1v[q]=att_b1[c]; attw2v[q]=att_W2[c]; }
  const float attb2 = att_b2[0];

  auto fuse = [&](int st){
    s16x8 a1[4], a2[4];
    #pragma unroll
    for (int ks=0;ks<2;ks++){
      a1[ks]=ldA(1,ks); a2[ks]=ldA(2,ks);
      s16x8 asub=ldA(st,ks); a1[2+ks]=asub; a2[2+ks]=asub;
    }
    f32x4 c1[4], c2[4];
    #pragma unroll
    for (int nt=0;nt<4;nt++){
      f32x4 x1={0.f,0.f,0.f,0.f}, x2={0.f,0.f,0.f,0.f};
      #pragma unroll
      for (int ks=0;ks<4;ks++){
        s16x8 b = *(const s16x8*)&pk8[(nt*4+ks)*64 + lane];
        x1 = mf(a1[ks], b, x1);
        x2 = mf(a2[ks], b, x2);
      }
      c1[nt]=x1; c2[nt]=x2;
    }
    float t1[4]={0.f,0.f,0.f,0.f}, t2[4]={0.f,0.f,0.f,0.f};
    #pragma unroll
    for (int nt=0;nt<4;nt++){
      #pragma unroll
      for (int r=0;r<4;r++){
        float h1=c1[nt][r]+attb1v[nt]; h1 = h1>0.f?h1:0.2f*h1;
        float h2=c2[nt][r]+attb1v[nt]; h2 = h2>0.f?h2:0.2f*h2;
        t1[r] += h1*attw2v[nt]; t2[r] += h2*attw2v[nt];
      }
    }
    #pragma unroll
    for (int r=0;r<4;r++){
      #pragma unroll
      for (int off=1; off<16; off<<=1){ t1[r]+=__shfl_xor(t1[r],off,64); t2[r]+=__shfl_xor(t2[r],off,64); }
    }
    if ((lane&15)==0){
      int g = lane>>4;
      #pragma unroll
      for (int r=0;r<4;r++){ wbuf[g*4+r] = sigm(t1[r]+attb2); wbuf[16+g*4+r] = sigm(t2[r]+attb2); }
    }
    // e1/e2 += sub * w[row]
    #pragma unroll
    for (int it=0; it<2; it++){
      int row = it*8 + (lane>>3);
      int off = ((lane&7)<<3) ^ ((row&7)<<3);
      u16x8 ue1 = *(const u16x8*)&ldsT[1][row][off];
      u16x8 ue2 = *(const u16x8*)&ldsT[2][row][off];
      u16x8 us  = *(const u16x8*)&ldsT[st][row][off];
      float wA = wbuf[row], wB = wbuf[16+row];
      u16x8 o1, o2;
      #pragma unroll
      for (int j=0;j<8;j++){
        float sv=b2f(us[j]);
        o1[j]=f2b(b2f(ue1[j]) + sv*wA);
        o2[j]=f2b(b2f(ue2[j]) + sv*wB);
      }
      *(u16x8*)&ldsT[1][row][off]=o1;
      *(u16x8*)&ldsT[2][row][off]=o2;
    }
  };
  fuse(4);   // csub
  fuse(5);   // psub

  // ---------------- LSTM (h lives in slot 4; csub is dead now) ----------------
  float biasv[16];
  #pragma unroll
  for (int nt=0;nt<16;nt++){ int c=(nt<<4)+(lane&15); biasv[nt]=b_ih[c]+b_hh[c]; }
  float cst[16];
  #pragma unroll
  for (int i=0;i<16;i++) cst[i]=0.f;

  auto step=[&](int xt, bool useH){
    s16x8 ax0=ldA(xt,0), ax1=ldA(xt,1);
    s16x8 ah0, ah1;
    if (useH){ ah0=ldA(4,0); ah1=ldA(4,1); }
    f32x4 acc[16];
    #pragma unroll
    for (int nt=0;nt<16;nt++){
      f32x4 a={0.f,0.f,0.f,0.f};
      a = mf(ax0, *(const s16x8*)&pk8[1024 + (nt*2+0)*64 + lane], a);
      a = mf(ax1, *(const s16x8*)&pk8[1024 + (nt*2+1)*64 + lane], a);
      if (useH){
        a = mf(ah0, *(const s16x8*)&pk8[3072 + (nt*2+0)*64 + lane], a);
        a = mf(ah1, *(const s16x8*)&pk8[3072 + (nt*2+1)*64 + lane], a);
      }
      acc[nt]=a;
    }
    #pragma unroll
    for (int q=0;q<4;q++){
      #pragma unroll
      for (int r=0;r<4;r++){
        float iv=sigm  (acc[q    ][r]+biasv[q]);
        float fv=sigm  (acc[4+q  ][r]+biasv[4+q]);
        float gv=tanhf_(acc[8+q  ][r]+biasv[8+q]);
        float ov=sigm  (acc[12+q ][r]+biasv[12+q]);
        float cc=fv*cst[q*4+r]+iv*gv;
        cst[q*4+r]=cc;
        float hv=ov*tanhf_(cc);
        int row=((lane>>4)<<2)+r;
        int col=(lane&15)+(q<<4);
        ldsT[4][row][col ^ ((row&7)<<3)] = f2b(hv);
      }
    }
  };
  step(0,false); step(1,true); step(2,true); step(3,true);

  // ---------------- MLP head ----------------
  float mlb1v[4], mlw2v[4];
  #pragma unroll
  for (int q=0;q<4;q++){ int c=(q<<4)+(lane&15); mlb1v[q]=mlp_b1[c]; mlw2v[q]=mlp_W2[c]; }
  const float mlb2 = mlp_b2[0];
  s16x8 ah0=ldA(4,0), ah1=ldA(4,1);
  f32x4 mac[4];
  #pragma unroll
  for (int nt=0;nt<4;nt++){
    f32x4 a={0.f,0.f,0.f,0.f};
    a = mf(ah0, *(const s16x8*)&pk8[5120 + (nt*2+0)*64 + lane], a);
    a = mf(ah1, *(const s16x8*)&pk8[5120 + (nt*2+1)*64 + lane], a);
    mac[nt]=a;
  }
  float tt[4]={0.f,0.f,0.f,0.f};
  #pragma unroll
  for (int nt=0;nt<4;nt++){
    #pragma unroll
    for (int r=0;r<4;r++){ float mv=mac[nt][r]+mlb1v[nt]; mv=mv>0.f?mv:0.f; tt[r]+=mv*mlw2v[nt]; }
  }
  #pragma unroll
  for (int r=0;r<4;r++){
    #pragma unroll
    for (int off=1; off<16; off<<=1) tt[r]+=__shfl_xor(tt[r],off,64);
  }
  if ((lane&15)==0){
    #pragma unroll
    for (int r=0;r<4;r++){
      int p = base + ((lane>>4)<<2) + r;
      if (p < P) out[p] = sigm(tt[r]+mlb2);
    }
  }
}

// ---------------------------------------------------------------------------
// fallback fused kernel if ws_size is too small
// ---------------------------------------------------------------------------
__global__ __launch_bounds__(64) void path_kernel_fused(
    const int* __restrict__ paths,
    const int* __restrict__ pat_fp_idx,  const uint8_t* __restrict__ pat_fp_mask,
    const int* __restrict__ pat_ipc_idx, const uint8_t* __restrict__ pat_ipc_mask,
    const int* __restrict__ pat_comp_idx,const uint8_t* __restrict__ pat_comp_mask,
    const int* __restrict__ comp_ind_idx,const uint8_t* __restrict__ comp_ind_mask,
    const int* __restrict__ comp_pat_idx,const uint8_t* __restrict__ comp_pat_mask,
    const float* __restrict__ company_emb, const float* __restrict__ patent_emb,
    const float* __restrict__ fp_emb, const float* __restrict__ ipc_emb,
    const float* __restrict__ ind_emb,
    const float* __restrict__ b_ih, const float* __restrict__ b_hh,
    const float* __restrict__ att_b1, const float* __restrict__ att_W2, const float* __restrict__ att_b2,
    const float* __restrict__ mlp_b1, const float* __restrict__ mlp_W2, const float* __restrict__ mlp_b2,
    const u16* __restrict__ pack,
    float* __restrict__ out, int P)
{
  __shared__ __align__(16) u16 ldsT[7][16][64];
  __shared__ float wbuf[32];
  const int lane = threadIdx.x;
  const int base = blockIdx.x * 16;
  if (base >= P) return;
  const u16x8* pk8 = (const u16x8*)pack;

  #pragma unroll 2
  for (int r=0;r<16;r++){
    int p = base + r; int ps = p < P ? p : (P-1);
    const int4 pq = *(const int4*)&paths[ps*4];
    float e0 = company_emb[(long)pq.x*64+lane];
    float e1 = patent_emb [(long)pq.y*64+lane];
    float e2 = fp_emb     [(long)pq.z*64+lane];
    float e3 = patent_emb [(long)pq.w*64+lane];
    float acc=0.f, cnt=0.f;
    #pragma unroll
    for (int jj=0;jj<4;jj++)
      if (comp_ind_mask[pq.x*4+jj]) { acc += ind_emb[(long)comp_ind_idx[pq.x*4+jj]*64+lane]; cnt += 1.f; }
    #pragma unroll
    for (int jj=0;jj<16;jj++)
      if (comp_pat_mask[pq.x*16+jj]){ acc += patent_emb[(long)comp_pat_idx[pq.x*16+jj]*64+lane]; cnt += 1.f; }
    float csub = e0 + acc/cnt;
    acc=0.f; cnt=0.f;
    #pragma unroll
    for (int jj=0;jj<2;jj++)
      if (pat_fp_mask[pq.w*2+jj])  { acc += fp_emb[(long)pat_fp_idx[pq.w*2+jj]*64+lane]; cnt += 1.f; }
    #pragma unroll
    for (int jj=0;jj<6;jj++)
      if (pat_ipc_mask[pq.w*6+jj]) { acc += ipc_emb[(long)pat_ipc_idx[pq.w*6+jj]*64+lane]; cnt += 1.f; }
    #pragma unroll
    for (int jj=0;jj<2;jj++)
      if (pat_comp_mask[pq.w*2+jj]){ acc += company_emb[(long)pat_comp_idx[pq.w*2+jj]*64+lane]; cnt += 1.f; }
    float psub = e3 + acc/cnt;
    int sc = lane ^ ((r&7)<<3);
    ldsT[0][r][sc]=f2b(e0); ldsT[1][r][sc]=f2b(e1); ldsT[2][r][sc]=f2b(e2);
    ldsT[3][r][sc]=f2b(e3); ldsT[4][r][sc]=f2b(csub); ldsT[5][r][sc]=f2b(psub);
  }

  auto ldA = [&](int t, int ks)->s16x8{
    int row = lane & 15;
    int off = (ks*32 + ((lane>>4)<<3)) ^ ((row&7)<<3);
    return *(const s16x8*)&ldsT[t][row][off];
  };

  float attb1v[4], attw2v[4];
  #pragma unroll
  for (int q=0;q<4;q++){ int c=(q<<4)+(lane&15); attb1v[q]=att_b1[c]; attw2v[q]=att_W2[c]; }
  const float attb2 = att_b2[0];

  auto fuse = [&](int st){
    s16x8 a1[4], a2[4];
    #pragma unroll
    for (int ks=0;ks<2;ks++){
      a1[ks]=ldA(1,ks); a2[ks]=ldA(2,ks);
      s16x8 asub=ldA(st,ks); a1[2+ks]=asub; a2[2+ks]=asub;
    }
    f32x4 c1[4], c2[4];
    #pragma unroll
    for (int nt=0;nt<4;nt++){
      f32x4 x1={0.f,0.f,0.f,0.f}, x2={0.f,0.f,0.f,0.f};
      #pragma unroll
      for (int ks=0;ks<4;ks++){
        s16x8 b = *(const s16x8*)&pk8[(nt*4+ks)*64 + lane];
        x1 = mf(a1[ks], b, x1);
        x2 = mf(a2[ks], b, x2);
      }
      c1[nt]=x1; c2[nt]=x2;
    }
    float t1[4]={0.f,0.f,0.f,0.f}, t2[4]={0.f,0.f,0.f,0.f};
    #pragma unroll
    for (int nt=0;nt<4;nt++){
      #pragma unroll
      for (int r=0;r<4;r++){
        float h1=c1[nt][r]+attb1v[nt]; h1 = h1>0.f?h1:0.2f*h1;
        float h2=c2[nt][r]+attb1v[nt]; h2 = h2>0.f?h2:0.2f*h2;
        t1[r] += h1*attw2v[nt]; t2[r] += h2*attw2v[nt];
      }
    }
    #pragma unroll
    for (int r=0;r<4;r++){
      #pragma unroll
      for (int off=1; off<16; off<<=1){ t1[r]+=__shfl_xor(t1[r],off,64); t2[r]+=__shfl_xor(t2[r],off,64); }
    }
    if ((lane&15)==0){
      int g = lane>>4;
      #pragma unroll
      for (int r=0;r<4;r++){ wbuf[g*4+r] = sigm(t1[r]+attb2); wbuf[16+g*4+r] = sigm(t2[r]+attb2); }
    }
    #pragma unroll
    for (int it=0; it<2; it++){
      int row = it*8 + (lane>>3);
      int off = ((lane&7)<<3) ^ ((row&7)<<3);
      u16x8 ue1 = *(const u16x8*)&ldsT[1][row][off];
      u16x8 ue2 = *(const u16x8*)&ldsT[2][row][off];
      u16x8 us  = *(const u16x8*)&ldsT[st][row][off];
      float wA = wbuf[row], wB = wbuf[16+row];
      u16x8 o1, o2;
      #pragma unroll
      for (int j=0;j<8;j++){
        float sv=b2f(us[j]);
        o1[j]=f2b(b2f(ue1[j]) + sv*wA);
        o2[j]=f2b(b2f(ue2[j]) + sv*wB);
      }
      *(u16x8*)&ldsT[1][row][off]=o1;
      *(u16x8*)&ldsT[2][row][off]=o2;
    }
  };
  fuse(4); fuse(5);

  float biasv[16];
  #pragma unroll
  for (int nt=0;nt<16;nt++){ int c=(nt<<4)+(lane&15); biasv[nt]=b_ih[c]+b_hh[c]; }
  float cst[16];
  #pragma unroll
  for (int i=0;i<16;i++) cst[i]=0.f;

  auto step=[&](int xt, bool useH){
    s16x8 ax0=ldA(xt,0), ax1=ldA(xt,1);
    s16x8 ah0, ah1;
    if (useH){ ah0=ldA(6,0); ah1=ldA(6,1); }
    f32x4 acc[16];
    #pragma unroll
    for (int nt=0;nt<16;nt++){
      f32x4 a={0.f,0.f,0.f,0.f};
      a = mf(ax0, *(const s16x8*)&pk8[1024 + (nt*2+0)*64 + lane], a);
      a = mf(ax1, *(const s16x8*)&pk8[1024 + (nt*2+1)*64 + lane], a);
      if (useH){
        a = mf(ah0, *(const s16x8*)&pk8[3072 + (nt*2+0)*64 + lane], a);
        a = mf(ah1, *(const s16x8*)&pk8[3072 + (nt*2+1)*64 + lane], a);
      }
      acc[nt]=a;
    }
    #pragma unroll
    for (int q=0;q<4;q++){
      #pragma unroll
      for (int r=0;r<4;r++){
        float iv=sigm  (acc[q    ][r]+biasv[q]);
        float fv=sigm  (acc[4+q  ][r]+biasv[4+q]);
        float gv=tanhf_(acc[8+q  ][r]+biasv[8+q]);
        float ov=sigm  (acc[12+q ][r]+biasv[12+q]);
        float cc=fv*cst[q*4+r]+iv*gv;
        cst[q*4+r]=cc;
        float hv=ov*tanhf_(cc);
        int row=((lane>>4)<<2)+r;
        int col=(lane&15)+(q<<4);
        ldsT[6][row][col ^ ((row&7)<<3)] = f2b(hv);
      }
    }
  };
  step(0,false); step(1,true); step(2,true); step(3,true);

  float mlb1v[4], mlw2v[4];
  #pragma unroll
  for (int q=0;q<4;q++){ int c=(q<<4)+(lane&15); mlb1v[q]=mlp_b1[c]; mlw2v[q]=mlp_W2[c]; }
  const float mlb2 = mlp_b2[0];
  s16x8 ah0=ldA(6,0), ah1=ldA(6,1);
  f32x4 mac[4];
  #pragma unroll
  for (int nt=0;nt<4;nt++){
    f32x4 a={0.f,0.f,0.f,0.f};
    a = mf(ah0, *(const s16x8*)&pk8[5120 + (nt*2+0)*64 + lane], a);
    a = mf(ah1, *(const s16x8*)&pk8[5120 + (nt*2+1)*64 + lane], a);
    mac[nt]=a;
  }
  float tt[4]={0.f,0.f,0.f,0.f};
  #pragma unroll
  for (int nt=0;nt<4;nt++){
    #pragma unroll
    for (int r=0;r<4;r++){ float mv=mac[nt][r]+mlb1v[nt]; mv=mv>0.f?mv:0.f; tt[r]+=mv*mlw2v[nt]; }
  }
  #pragma unroll
  for (int r=0;r<4;r++){
    #pragma unroll
    for (int off=1; off<16; off<<=1) tt[r]+=__shfl_xor(tt[r],off,64);
  }
  if ((lane&15)==0){
    #pragma unroll
    for (int r=0;r<4;r++){
      int p = base + ((lane>>4)<<2) + r;
      if (p < P) out[p] = sigm(tt[r]+mlb2);
    }
  }
}

extern "C" void kernel_launch(void* const* d_in, const int* in_sizes, int n_in,
                              void* d_out, int out_size, void* d_ws, size_t ws_size,
                              hipStream_t stream){
  const int*     paths         = (const int*)    d_in[0];
  const int*     pat_fp_idx    = (const int*)    d_in[2];
  const uint8_t* pat_fp_mask   = (const uint8_t*)d_in[3];
  const int*     pat_ipc_idx   = (const int*)    d_in[4];
  const uint8_t* pat_ipc_mask  = (const uint8_t*)d_in[5];
  const int*     pat_comp_idx  = (const int*)    d_in[6];
  const uint8_t* pat_comp_mask = (const uint8_t*)d_in[7];
  const int*     comp_ind_idx  = (const int*)    d_in[8];
  const uint8_t* comp_ind_mask = (const uint8_t*)d_in[9];
  const int*     comp_pat_idx  = (const int*)    d_in[10];
  const uint8_t* comp_pat_mask = (const uint8_t*)d_in[11];
  const float*   company_emb   = (const float*)  d_in[12];
  const float*   patent_emb    = (const float*)  d_in[13];
  const float*   fp_emb        = (const float*)  d_in[14];
  const float*   ipc_emb       = (const float*)  d_in[15];
  const float*   ind_emb       = (const float*)  d_in[16];
  const float*   W_ih          = (const float*)  d_in[17];
  const float*   W_hh          = (const float*)  d_in[18];
  const float*   b_ih          = (const float*)  d_in[19];
  const float*   b_hh          = (const float*)  d_in[20];
  const float*   att_W1        = (const float*)  d_in[21];
  const float*   att_b1        = (const float*)  d_in[22];
  const float*   att_W2        = (const float*)  d_in[23];
  const float*   att_b2        = (const float*)  d_in[24];
  const float*   mlp_W1        = (const float*)  d_in[25];
  const float*   mlp_b1        = (const float*)  d_in[26];
  const float*   mlp_W2        = (const float*)  d_in[27];
  const float*   mlp_b2        = (const float*)  d_in[28];
  float* out = (float*)d_out;
  const int P = in_sizes[1];

  u16* pack = (u16*)d_ws;                       // 90112 B
  const size_t packB = 5632u * 16u;
  const int tiles = (P + 15) / 16;
  const int total = tiles * 16;
  const size_t need = packB + (size_t)tiles * 12288u;

  if (ws_size >= need){
    u16* tileimg = (u16*)((char*)d_ws + packB);
    // prep is folded into the first 22 blocks of gather (pack consumed only
    // by path_kernel_fast -> inter-kernel ordering is the only sync needed).
    gather_kernel<<<tiles*4, 256, 0, stream>>>(
        paths,
        pat_fp_idx, pat_fp_mask, pat_ipc_idx, pat_ipc_mask, pat_comp_idx, pat_comp_mask,
        comp_ind_idx, comp_ind_mask, comp_pat_idx, comp_pat_mask,
        company_emb, patent_emb, fp_emb, ipc_emb, ind_emb,
        att_W1, W_ih, W_hh, mlp_W1, pack,
        tileimg, P, total);
    path_kernel_fast<<<tiles, 64, 0, stream>>>(
        b_ih, b_hh, att_b1, att_W2, att_b2,
        mlp_b1, mlp_W2, mlp_b2,
        pack, tileimg, out, P);
  } else {
    prep_kernel<<<22, 256, 0, stream>>>(att_W1, W_ih, W_hh, mlp_W1, pack);
    path_kernel_fused<<<tiles, 64, 0, stream>>>(
        paths,
        pat_fp_idx, pat_fp_mask, pat_ipc_idx, pat_ipc_mask, pat_comp_idx, pat_comp_mask,
        comp_ind_idx, comp_ind_mask, comp_pat_idx, comp_pat_mask,
        company_emb, patent_emb, fp_emb, ipc_emb, ind_emb,
        b_ih, b_hh, att_b1, att_W2, att_b2,
        mlp_b1, mlp_W2, mlp_b2,
        pack, out, P);
  }
}